// Round 13
// baseline (39.131 us; speedup 1.0000x reference)
//
#include <hip/hip_runtime.h>
#include <hip/hip_bf16.h>

#define NB 32
#define NP 4096
#define NC 128
#define ND 128
#define TP 64             // points per block (16 per wave)
#define EPSV 1e-16f

typedef __attribute__((ext_vector_type(8))) short short8;
typedef __attribute__((ext_vector_type(4))) short short4v;
typedef __attribute__((ext_vector_type(4))) float f32x4;

__device__ __forceinline__ unsigned short f2bf(float f) {
  __hip_bfloat16 h = __float2bfloat16(f);
  return *reinterpret_cast<unsigned short*>(&h);
}

// LDS byte-offset swizzle: row-major [row][128 bf16], XOR (row&7)<<4.
// Phase-2 a8 reads (16 rows at one column-slice) spread 8 bank-quads with
// 2-way alias (free, m136); staging ds_writes land 8-way (2.94x) - tolerable.
__device__ __forceinline__ int swz(int row, int kbyte) {
  return (row * 256 + kbyte) ^ ((row & 7) << 4);
}

// R13 = R12 (single-launch, zero-store barrier, wave-local wT, swapped MFMA)
// + (a) pos/q register loads issued BEFORE staging (latency hides under the
//       64 staging cvts instead of being exposed at the barrier), and
// + (b) __launch_bounds__(256,3): guarantees allocator fits 3 waves/SIMD
//       (~170 VGPR cap; audited live set ~110, no spill) so the 48KB-LDS
//       limit of 3 blocks/CU is actually reachable.
__global__ __launch_bounds__(256, 3) void cc_all(
    const int* __restrict__ indices,
    const float* __restrict__ qp,       // (B,P,3)
    const float* __restrict__ cpos,     // (R,C,3)
    const float* __restrict__ codes,    // (R,C,D)
    const void* __restrict__ dsp,       // dist_scale scalar
    float* __restrict__ out_qc,         // (B,P,D)
    float* __restrict__ out_sq,         // (B,P,C)
    float* __restrict__ out_wt) {       // (B,P,C)
  __shared__ __align__(16) unsigned char cT[ND * NC * 2];   // 32KB [d][c] swz
  __shared__ __align__(16) unsigned char wT[TP * NC * 2];   // 16KB, 4KB/wave

  const int tid = threadIdx.x;
  const int lane = tid & 63;
  const int wv = tid >> 6;
  const int g = lane >> 4;            // point-within-quad (phase 1)
  const int l16 = lane & 15;
  const int b = blockIdx.x >> 6;
  const int p0 = (blockIdx.x & 63) * TP;
  const int rec = indices[b];
  unsigned char* wTw = wT + wv * (16 * 256); // this wave's 16-row section

  const int si = ((const int*)dsp)[0];
  const float sv = (si > 0 && si < 1000) ? (float)si : ((const float*)dsp)[0];

  // ---- (a) independent register loads FIRST: their latency hides under the
  // staging loop's load+cvt work below.
  const float* pb0 = cpos + ((size_t)rec * NC + l16 * 4) * 3;
  const float* pb1 = cpos + ((size_t)rec * NC + 64 + l16 * 4) * 3;
  float px[8], py[8], pz[8];
  #pragma unroll
  for (int j = 0; j < 4; ++j) {
    px[j] = pb0[j * 3 + 0]; py[j] = pb0[j * 3 + 1]; pz[j] = pb0[j * 3 + 2];
    px[j + 4] = pb1[j * 3 + 0]; py[j + 4] = pb1[j * 3 + 1]; pz[j + 4] = pb1[j * 3 + 2];
  }

  const size_t rowbase = (size_t)b * NP + p0;
  float qx[4], qy[4], qz[4];
  #pragma unroll
  for (int it = 0; it < 4; ++it) {
    const int p = wv * 16 + it * 4 + g;
    const float* q = qp + (rowbase + p) * 3;
    qx[it] = q[0]; qy[it] = q[1]; qz[it] = q[2];
  }

  // ---- inline cT staging: thread owns row d = tid&127, c-range (tid>>7)*64.
  // Loads: cb[c*128 + d] — consecutive lanes -> consecutive d -> 256B/instr.
  // Writes: 8 x ds_write_b128 (8 bf16 along c within row d, swizzled).
  const float* cb = codes + (size_t)rec * (NC * ND);
  {
    const int d = tid & 127;
    const int c0s = (tid >> 7) * 64;
    const float* cbrow = cb + d;
    #pragma unroll
    for (int o = 0; o < 8; ++o) {
      short8 v;
      #pragma unroll
      for (int j = 0; j < 8; ++j)
        v[j] = (short)f2bf(cbrow[(size_t)(c0s + o * 8 + j) * ND]);
      *(short8*)(cT + swz(d, (c0s + o * 8) * 2)) = v;
    }
  }

  __syncthreads();   // ONLY barrier: drains staging + register loads.
                     // Zero global stores in flight here.

  // ---- phase 1: wave-local points; lane owns 8 codes (4+4 split).
  const bool s2 = (sv == 2.0f);
  #pragma unroll
  for (int it = 0; it < 4; ++it) {
    const int p = wv * 16 + it * 4 + g;
    float dd[8], wu[8];
    #pragma unroll
    for (int j = 0; j < 8; ++j) {
      const float dx = qx[it] - px[j], dy = qy[it] - py[j], dz = qz[it] - pz[j];
      dd[j] = fmaf(dx, dx, fmaf(dy, dy, dz * dz)) + EPSV;
    }
    if (s2) {
      #pragma unroll
      for (int j = 0; j < 8; ++j) wu[j] = __builtin_amdgcn_rcpf(dd[j]);
    } else {
      #pragma unroll
      for (int j = 0; j < 8; ++j) wu[j] = __powf(dd[j], -0.5f * sv);
    }
    float s = ((wu[0] + wu[1]) + (wu[2] + wu[3])) + ((wu[4] + wu[5]) + (wu[6] + wu[7]));
    s += __shfl_xor(s, 1); s += __shfl_xor(s, 2);
    s += __shfl_xor(s, 4); s += __shfl_xor(s, 8);   // within 16-lane group
    const float inv = __builtin_amdgcn_rcpf(s);

    f32x4 dlo, dhi, wlo, whi;
    #pragma unroll
    for (int j = 0; j < 4; ++j) {
      dlo[j] = dd[j]; dhi[j] = dd[j + 4];
      wlo[j] = wu[j] * inv; whi[j] = wu[j + 4] * inv;
    }
    const size_t rb = (rowbase + p) * (size_t)NC;
    *(f32x4*)(out_sq + rb + l16 * 4) = dlo;
    *(f32x4*)(out_sq + rb + 64 + l16 * 4) = dhi;
    *(f32x4*)(out_wt + rb + l16 * 4) = wlo;
    *(f32x4*)(out_wt + rb + 64 + l16 * 4) = whi;

    short4v wbl, wbh;
    #pragma unroll
    for (int j = 0; j < 4; ++j) {
      wbl[j] = (short)f2bf(wlo[j]);
      wbh[j] = (short)f2bf(whi[j]);
    }
    const int r = it * 4 + g;
    *(short4v*)(wTw + swz(r, l16 * 8)) = wbl;        // codes l16*4..+3
    *(short4v*)(wTw + swz(r, 128 + l16 * 8)) = wbh;  // codes 64+l16*4..+3
  }

  // ---- phase 2: no further barrier (wT is wave-local; cT synced above).
  // Phase-1 stores drain underneath the MFMA.
  const int kg = lane >> 4;
  const int prl = wv * 16 + l16;       // this lane's point (local)
  f32x4 acc[8];
  #pragma unroll
  for (int mi = 0; mi < 8; ++mi) acc[mi] = (f32x4){0.f, 0.f, 0.f, 0.f};

  #pragma unroll
  for (int kk = 0; kk < NC; kk += 32) {
    const int kb = (kk + kg * 8) * 2;
    const short8 b0 = *(const short8*)(wTw + swz(l16, kb));
    #pragma unroll
    for (int mi = 0; mi < 8; ++mi) {
      const short8 a8 = *(const short8*)(cT + swz(mi * 16 + l16, kb));
      acc[mi] = __builtin_amdgcn_mfma_f32_16x16x32_bf16(a8, b0, acc[mi], 0, 0, 0);
    }
  }

  // D layout: col(=p-offset) = lane&15, row(=d-offset) = (lane>>4)*4 + reg
  float* o0 = out_qc + (rowbase + prl) * (size_t)ND + kg * 4;
  #pragma unroll
  for (int mi = 0; mi < 8; ++mi)
    *(f32x4*)(o0 + mi * 16) = acc[mi];
}

extern "C" void kernel_launch(void* const* d_in, const int* in_sizes, int n_in,
                              void* d_out, int out_size, void* d_ws, size_t ws_size,
                              hipStream_t stream) {
  const int* indices = (const int*)d_in[0];
  const float* qp = (const float*)d_in[1];
  const float* cpos = (const float*)d_in[2];
  const float* codes = (const float*)d_in[3];
  const void* dsp = d_in[4];

  float* out = (float*)d_out;
  float* qc = out;                                   // (B,P,D)
  float* sq = qc + (size_t)NB * NP * ND;             // (B,P,C)
  float* wt = sq + (size_t)NB * NP * NC;             // (B,P,C)

  dim3 grid(NB * (NP / TP));                         // 2048 blocks, 1 launch
  cc_all<<<grid, 256, 0, stream>>>(indices, qp, cpos, codes, dsp, qc, sq, wt);
}

// Round 14
// 38.176 us; speedup vs baseline: 1.0250x; 1.0250x over previous
//
#include <hip/hip_runtime.h>
#include <hip/hip_bf16.h>

#define NB 32
#define NP 4096
#define NC 128
#define ND 128
#define TP 64             // points per block (16 per wave)
#define EPSV 1e-16f

typedef __attribute__((ext_vector_type(8))) short short8;
typedef __attribute__((ext_vector_type(4))) short short4v;
typedef __attribute__((ext_vector_type(4))) float f32x4;

__device__ __forceinline__ unsigned short f2bf(float f) {
  __hip_bfloat16 h = __float2bfloat16(f);
  return *reinterpret_cast<unsigned short*>(&h);
}

// LDS byte-offset swizzle: row-major [row][128 bf16], XOR (row&7)<<4.
__device__ __forceinline__ int swz(int row, int kbyte) {
  return (row * 256 + kbyte) ^ ((row & 7) << 4);
}

// R14 = R12 (best, 39.0us: single-launch, zero-store barrier, wave-local wT,
// swapped MFMA) + XCD-aware record mapping (T1): blocks of the same record
// land on the SAME XCD (hardware round-robins consecutive blockIdx across
// XCDs), so each XCD's L2 holds 4 records (256KB) instead of all 32 (2MB);
// HBM codes re-fetch drops 8x2MB -> 2MB and the read stream stops competing
// with the 201MB write stream in L2. Bijective: 2048 = 8 XCD x 4 rec x 64 tile.
__global__ __launch_bounds__(256, 2) void cc_all(
    const int* __restrict__ indices,
    const float* __restrict__ qp,       // (B,P,3)
    const float* __restrict__ cpos,     // (R,C,3)
    const float* __restrict__ codes,    // (R,C,D)
    const void* __restrict__ dsp,       // dist_scale scalar
    float* __restrict__ out_qc,         // (B,P,D)
    float* __restrict__ out_sq,         // (B,P,C)
    float* __restrict__ out_wt) {       // (B,P,C)
  __shared__ __align__(16) unsigned char cT[ND * NC * 2];   // 32KB [d][c] swz
  __shared__ __align__(16) unsigned char wT[TP * NC * 2];   // 16KB, 4KB/wave

  const int tid = threadIdx.x;
  const int lane = tid & 63;
  const int wv = tid >> 6;
  const int g = lane >> 4;            // point-within-quad (phase 1)
  const int l16 = lane & 15;

  // ---- XCD-aware mapping (the only change vs R12)
  const int bid = blockIdx.x;
  const int xcd = bid & 7;            // hw round-robin: consecutive bid -> xcd
  const int li = bid >> 3;            // 0..255 within this XCD
  const int b = xcd * 4 + (li >> 6);  // 4 records per XCD
  const int p0 = (li & 63) * TP;

  const int rec = indices[b];
  unsigned char* wTw = wT + wv * (16 * 256); // this wave's 16-row section

  const int si = ((const int*)dsp)[0];
  const float sv = (si > 0 && si < 1000) ? (float)si : ((const float*)dsp)[0];

  // ---- inline cT staging: thread owns row d = tid&127, c-range (tid>>7)*64.
  // Loads: cb[c*128 + d] — consecutive lanes -> consecutive d -> 256B/instr.
  // Writes: 8 x ds_write_b128 (8 bf16 along c within row d, swizzled).
  const float* cb = codes + (size_t)rec * (NC * ND);
  {
    const int d = tid & 127;
    const int c0s = (tid >> 7) * 64;
    const float* cbrow = cb + d;
    #pragma unroll
    for (int o = 0; o < 8; ++o) {
      short8 v;
      #pragma unroll
      for (int j = 0; j < 8; ++j)
        v[j] = (short)f2bf(cbrow[(size_t)(c0s + o * 8 + j) * ND]);
      *(short8*)(cT + swz(d, (c0s + o * 8) * 2)) = v;
    }
  }

  // ---- per-lane code positions: lane owns codes l16*4..+3 and 64+l16*4..+3
  const float* pb0 = cpos + ((size_t)rec * NC + l16 * 4) * 3;
  const float* pb1 = cpos + ((size_t)rec * NC + 64 + l16 * 4) * 3;
  float px[8], py[8], pz[8];
  #pragma unroll
  for (int j = 0; j < 4; ++j) {
    px[j] = pb0[j * 3 + 0]; py[j] = pb0[j * 3 + 1]; pz[j] = pb0[j * 3 + 2];
    px[j + 4] = pb1[j * 3 + 0]; py[j + 4] = pb1[j * 3 + 1]; pz[j + 4] = pb1[j * 3 + 2];
  }

  // ---- q for this wave's 16 points: p = wv*16 + it*4 + g
  const size_t rowbase = (size_t)b * NP + p0;
  float qx[4], qy[4], qz[4];
  #pragma unroll
  for (int it = 0; it < 4; ++it) {
    const int p = wv * 16 + it * 4 + g;
    const float* q = qp + (rowbase + p) * 3;
    qx[it] = q[0]; qy[it] = q[1]; qz[it] = q[2];
  }

  __syncthreads();   // ONLY barrier: drains staging loads/LDS writes + the
                     // q/pos register loads. Zero global stores in flight.

  // ---- phase 1: wave-local points; lane owns 8 codes (4+4 split).
  const bool s2 = (sv == 2.0f);
  #pragma unroll
  for (int it = 0; it < 4; ++it) {
    const int p = wv * 16 + it * 4 + g;
    float dd[8], wu[8];
    #pragma unroll
    for (int j = 0; j < 8; ++j) {
      const float dx = qx[it] - px[j], dy = qy[it] - py[j], dz = qz[it] - pz[j];
      dd[j] = fmaf(dx, dx, fmaf(dy, dy, dz * dz)) + EPSV;
    }
    if (s2) {
      #pragma unroll
      for (int j = 0; j < 8; ++j) wu[j] = __builtin_amdgcn_rcpf(dd[j]);
    } else {
      #pragma unroll
      for (int j = 0; j < 8; ++j) wu[j] = __powf(dd[j], -0.5f * sv);
    }
    float s = ((wu[0] + wu[1]) + (wu[2] + wu[3])) + ((wu[4] + wu[5]) + (wu[6] + wu[7]));
    s += __shfl_xor(s, 1); s += __shfl_xor(s, 2);
    s += __shfl_xor(s, 4); s += __shfl_xor(s, 8);   // within 16-lane group
    const float inv = __builtin_amdgcn_rcpf(s);

    f32x4 dlo, dhi, wlo, whi;
    #pragma unroll
    for (int j = 0; j < 4; ++j) {
      dlo[j] = dd[j]; dhi[j] = dd[j + 4];
      wlo[j] = wu[j] * inv; whi[j] = wu[j + 4] * inv;
    }
    const size_t rb = (rowbase + p) * (size_t)NC;
    *(f32x4*)(out_sq + rb + l16 * 4) = dlo;
    *(f32x4*)(out_sq + rb + 64 + l16 * 4) = dhi;
    *(f32x4*)(out_wt + rb + l16 * 4) = wlo;
    *(f32x4*)(out_wt + rb + 64 + l16 * 4) = whi;

    short4v wbl, wbh;
    #pragma unroll
    for (int j = 0; j < 4; ++j) {
      wbl[j] = (short)f2bf(wlo[j]);
      wbh[j] = (short)f2bf(whi[j]);
    }
    const int r = it * 4 + g;
    *(short4v*)(wTw + swz(r, l16 * 8)) = wbl;        // codes l16*4..+3
    *(short4v*)(wTw + swz(r, 128 + l16 * 8)) = wbh;  // codes 64+l16*4..+3
  }

  // ---- phase 2: no further barrier (wT is wave-local; cT synced above).
  // Phase-1 stores drain underneath the MFMA.
  const int kg = lane >> 4;
  const int prl = wv * 16 + l16;       // this lane's point (local)
  f32x4 acc[8];
  #pragma unroll
  for (int mi = 0; mi < 8; ++mi) acc[mi] = (f32x4){0.f, 0.f, 0.f, 0.f};

  #pragma unroll
  for (int kk = 0; kk < NC; kk += 32) {
    const int kb = (kk + kg * 8) * 2;
    const short8 b0 = *(const short8*)(wTw + swz(l16, kb));
    #pragma unroll
    for (int mi = 0; mi < 8; ++mi) {
      const short8 a8 = *(const short8*)(cT + swz(mi * 16 + l16, kb));
      acc[mi] = __builtin_amdgcn_mfma_f32_16x16x32_bf16(a8, b0, acc[mi], 0, 0, 0);
    }
  }

  // D layout: col(=p-offset) = lane&15, row(=d-offset) = (lane>>4)*4 + reg
  float* o0 = out_qc + (rowbase + prl) * (size_t)ND + kg * 4;
  #pragma unroll
  for (int mi = 0; mi < 8; ++mi)
    *(f32x4*)(o0 + mi * 16) = acc[mi];
}

extern "C" void kernel_launch(void* const* d_in, const int* in_sizes, int n_in,
                              void* d_out, int out_size, void* d_ws, size_t ws_size,
                              hipStream_t stream) {
  const int* indices = (const int*)d_in[0];
  const float* qp = (const float*)d_in[1];
  const float* cpos = (const float*)d_in[2];
  const float* codes = (const float*)d_in[3];
  const void* dsp = d_in[4];

  float* out = (float*)d_out;
  float* qc = out;                                   // (B,P,D)
  float* sq = qc + (size_t)NB * NP * ND;             // (B,P,C)
  float* wt = sq + (size_t)NB * NP * NC;             // (B,P,C)

  dim3 grid(NB * (NP / TP));                         // 2048 blocks, 1 launch
  cc_all<<<grid, 256, 0, stream>>>(indices, qp, cpos, codes, dsp, qc, sq, wt);
}

// Round 15
// 37.790 us; speedup vs baseline: 1.0355x; 1.0102x over previous
//
#include <hip/hip_runtime.h>
#include <hip/hip_bf16.h>

#define NB 32
#define NP 4096
#define NC 128
#define ND 128
#define TP 64             // points per block (16 per wave)
#define EPSV 1e-16f

typedef __attribute__((ext_vector_type(8))) short short8;
typedef __attribute__((ext_vector_type(4))) short short4v;
typedef __attribute__((ext_vector_type(4))) float f32x4;

__device__ __forceinline__ unsigned short f2bf(float f) {
  __hip_bfloat16 h = __float2bfloat16(f);
  return *reinterpret_cast<unsigned short*>(&h);
}

// LDS byte-offset swizzle: row-major [row][128 bf16], XOR (row&7)<<4.
__device__ __forceinline__ int swz(int row, int kbyte) {
  return (row * 256 + kbyte) ^ ((row & 7) << 4);
}

// R15 = R14 (38.2us: single-launch, XCD-aware record mapping, zero-store
// barrier, wave-local wT, swapped MFMA) + DENSE phase-1 stores:
// 32-lane point ownership -> every f32x4 store instruction covers two
// complete contiguous 512B rows (1KB dense) instead of four quarter-rows
// at stride 512B. Same instruction count; +1 shfl level; wT values and
// layout unchanged; phase 2 untouched.
__global__ __launch_bounds__(256, 2) void cc_all(
    const int* __restrict__ indices,
    const float* __restrict__ qp,       // (B,P,3)
    const float* __restrict__ cpos,     // (R,C,3)
    const float* __restrict__ codes,    // (R,C,D)
    const void* __restrict__ dsp,       // dist_scale scalar
    float* __restrict__ out_qc,         // (B,P,D)
    float* __restrict__ out_sq,         // (B,P,C)
    float* __restrict__ out_wt) {       // (B,P,C)
  __shared__ __align__(16) unsigned char cT[ND * NC * 2];   // 32KB [d][c] swz
  __shared__ __align__(16) unsigned char wT[TP * NC * 2];   // 16KB, 4KB/wave

  const int tid = threadIdx.x;
  const int lane = tid & 63;
  const int wv = tid >> 6;
  const int l16 = lane & 15;
  const int l32 = lane & 31;          // phase-1: code-group within point
  const int h = lane >> 5;            // phase-1: point parity (0/1)

  // ---- XCD-aware mapping (validated R14)
  const int bid = blockIdx.x;
  const int xcd = bid & 7;
  const int li = bid >> 3;
  const int b = xcd * 4 + (li >> 6);  // 4 records per XCD
  const int p0 = (li & 63) * TP;

  const int rec = indices[b];
  unsigned char* wTw = wT + wv * (16 * 256); // this wave's 16-row section

  const int si = ((const int*)dsp)[0];
  const float sv = (si > 0 && si < 1000) ? (float)si : ((const float*)dsp)[0];

  // ---- inline cT staging: thread owns row d = tid&127, c-range (tid>>7)*64.
  const float* cb = codes + (size_t)rec * (NC * ND);
  {
    const int d = tid & 127;
    const int c0s = (tid >> 7) * 64;
    const float* cbrow = cb + d;
    #pragma unroll
    for (int o = 0; o < 8; ++o) {
      short8 v;
      #pragma unroll
      for (int j = 0; j < 8; ++j)
        v[j] = (short)f2bf(cbrow[(size_t)(c0s + o * 8 + j) * ND]);
      *(short8*)(cT + swz(d, (c0s + o * 8) * 2)) = v;
    }
  }

  // ---- per-lane code positions: lane owns codes l32*4..+3 (4 codes)
  const float* pb = cpos + ((size_t)rec * NC + l32 * 4) * 3;
  float px[4], py[4], pz[4];
  #pragma unroll
  for (int j = 0; j < 4; ++j) {
    px[j] = pb[j * 3 + 0]; py[j] = pb[j * 3 + 1]; pz[j] = pb[j * 3 + 2];
  }

  // ---- q for this wave's 16 points: p = wv*16 + it*2 + h
  const size_t rowbase = (size_t)b * NP + p0;
  float qx[8], qy[8], qz[8];
  #pragma unroll
  for (int it = 0; it < 8; ++it) {
    const int p = wv * 16 + it * 2 + h;
    const float* q = qp + (rowbase + p) * 3;
    qx[it] = q[0]; qy[it] = q[1]; qz[it] = q[2];
  }

  __syncthreads();   // ONLY barrier: drains staging + register loads.
                     // Zero global stores in flight here.

  // ---- phase 1: 32-lane group owns one point; lane owns 4 codes.
  const bool s2 = (sv == 2.0f);
  #pragma unroll
  for (int it = 0; it < 8; ++it) {
    const int p = wv * 16 + it * 2 + h;
    float dd[4], wu[4];
    #pragma unroll
    for (int j = 0; j < 4; ++j) {
      const float dx = qx[it] - px[j], dy = qy[it] - py[j], dz = qz[it] - pz[j];
      dd[j] = fmaf(dx, dx, fmaf(dy, dy, dz * dz)) + EPSV;
    }
    if (s2) {
      #pragma unroll
      for (int j = 0; j < 4; ++j) wu[j] = __builtin_amdgcn_rcpf(dd[j]);
    } else {
      #pragma unroll
      for (int j = 0; j < 4; ++j) wu[j] = __powf(dd[j], -0.5f * sv);
    }
    float s = (wu[0] + wu[1]) + (wu[2] + wu[3]);
    s += __shfl_xor(s, 1); s += __shfl_xor(s, 2);
    s += __shfl_xor(s, 4); s += __shfl_xor(s, 8);
    s += __shfl_xor(s, 16);            // stays within the 32-lane group
    const float inv = __builtin_amdgcn_rcpf(s);

    f32x4 dv, wv4;
    #pragma unroll
    for (int j = 0; j < 4; ++j) { dv[j] = dd[j]; wv4[j] = wu[j] * inv; }

    // Dense stores: lanes 0-31 cover row p (512B), lanes 32-63 row p+1
    // -> each instruction is 1KB fully contiguous.
    const size_t rb = (rowbase + p) * (size_t)NC + l32 * 4;
    *(f32x4*)(out_sq + rb) = dv;
    *(f32x4*)(out_wt + rb) = wv4;

    short4v wb;
    #pragma unroll
    for (int j = 0; j < 4; ++j) wb[j] = (short)f2bf(wv4[j]);
    const int r = it * 2 + h;          // local row (same wT layout as R14)
    *(short4v*)(wTw + swz(r, l32 * 8)) = wb;
  }

  // ---- phase 2: no further barrier (wT wave-local; cT synced above).
  // Phase-1 stores drain underneath the MFMA.  (unchanged from R14)
  const int kg = lane >> 4;
  const int prl = wv * 16 + l16;       // this lane's point (local)
  f32x4 acc[8];
  #pragma unroll
  for (int mi = 0; mi < 8; ++mi) acc[mi] = (f32x4){0.f, 0.f, 0.f, 0.f};

  #pragma unroll
  for (int kk = 0; kk < NC; kk += 32) {
    const int kb = (kk + kg * 8) * 2;
    const short8 b0 = *(const short8*)(wTw + swz(l16, kb));
    #pragma unroll
    for (int mi = 0; mi < 8; ++mi) {
      const short8 a8 = *(const short8*)(cT + swz(mi * 16 + l16, kb));
      acc[mi] = __builtin_amdgcn_mfma_f32_16x16x32_bf16(a8, b0, acc[mi], 0, 0, 0);
    }
  }

  // D layout: col(=p-offset) = lane&15, row(=d-offset) = (lane>>4)*4 + reg
  float* o0 = out_qc + (rowbase + prl) * (size_t)ND + kg * 4;
  #pragma unroll
  for (int mi = 0; mi < 8; ++mi)
    *(f32x4*)(o0 + mi * 16) = acc[mi];
}

extern "C" void kernel_launch(void* const* d_in, const int* in_sizes, int n_in,
                              void* d_out, int out_size, void* d_ws, size_t ws_size,
                              hipStream_t stream) {
  const int* indices = (const int*)d_in[0];
  const float* qp = (const float*)d_in[1];
  const float* cpos = (const float*)d_in[2];
  const float* codes = (const float*)d_in[3];
  const void* dsp = d_in[4];

  float* out = (float*)d_out;
  float* qc = out;                                   // (B,P,D)
  float* sq = qc + (size_t)NB * NP * ND;             // (B,P,C)
  float* wt = sq + (size_t)NB * NP * NC;             // (B,P,C)

  dim3 grid(NB * (NP / TP));                         // 2048 blocks, 1 launch
  cc_all<<<grid, 256, 0, stream>>>(indices, qp, cpos, codes, dsp, qc, sq, wt);
}